// Round 12
// baseline (841.932 us; speedup 1.0000x reference)
//
#include <hip/hip_runtime.h>

#define WN 32          // WIDTH
#define HID 8          // WIDTH/4
#define DEPTH 4
#define GPB 16         // node-groups per block (16 threads x 2 channels each) — R6-proven

typedef float fvec4 __attribute__((ext_vector_type(4)));

__global__ void zero_kernel(int* __restrict__ cnt, int n) {
    int i = blockIdx.x * blockDim.x + threadIdx.x;
    if (i < n) cnt[i] = 0;
}

// One atomic pass: per-node degree (cnt) AND each edge's within-segment rank.
__global__ void rank_kernel(const int* __restrict__ eidx, int* __restrict__ cnt,
                            int* __restrict__ rank, int e_cnt) {
    int e = blockIdx.x * blockDim.x + threadIdx.x;
    if (e >= e_cnt) return;
    rank[e] = atomicAdd(&cnt[eidx[e_cnt + e]], 1);
}

// --- 3-kernel parallel scan of cnt -> row_ptr (R8-proven) ---
__global__ void scan1_kernel(const int* __restrict__ cnt, int* __restrict__ blk_sum, int n) {
    __shared__ int s_wave[4];
    int t = threadIdx.x;
    int lane = t & 63, wv = t >> 6;
    int i = blockIdx.x * 256 + t;
    int v = (i < n) ? cnt[i] : 0;
#pragma unroll
    for (int d = 1; d < 64; d <<= 1) v += __shfl_xor(v, d, 64);
    if (lane == 0) s_wave[wv] = v;
    __syncthreads();
    if (t == 0) blk_sum[blockIdx.x] = s_wave[0] + s_wave[1] + s_wave[2] + s_wave[3];
}

__global__ void scan2_kernel(const int* __restrict__ blk_sum, int* __restrict__ blk_base, int nblk) {
    __shared__ int s_wave[4];
    int t = threadIdx.x;
    int lane = t & 63, wv = t >> 6;
    int offset = 0;
    for (int base = 0; base < nblk; base += 256) {
        int i = base + t;
        int v = (i < nblk) ? blk_sum[i] : 0;
        int x = v;
#pragma unroll
        for (int d = 1; d < 64; d <<= 1) {
            int y = __shfl_up(x, d, 64);
            if (lane >= d) x += y;
        }
        if (lane == 63) s_wave[wv] = x;
        __syncthreads();
        if (wv == 0 && lane < 4) {
            int y = s_wave[lane];
#pragma unroll
            for (int d = 1; d < 4; d <<= 1) {
                int z = __shfl_up(y, d, 64);
                if (lane >= d) y += z;
            }
            s_wave[lane] = y;
        }
        __syncthreads();
        int waveoff = (wv > 0) ? s_wave[wv - 1] : 0;
        int total = s_wave[3];
        if (i < nblk) blk_base[i] = x + waveoff + offset - v;   // exclusive
        offset += total;
        __syncthreads();
    }
}

__global__ void scan3_kernel(const int* __restrict__ cnt, const int* __restrict__ blk_base,
                             int* __restrict__ row_ptr, float* __restrict__ inv, int n) {
    __shared__ int s_wave[4];
    int t = threadIdx.x;
    int lane = t & 63, wv = t >> 6;
    int i = blockIdx.x * 256 + t;
    int v = (i < n) ? cnt[i] : 0;
    int x = v;
#pragma unroll
    for (int d = 1; d < 64; d <<= 1) {
        int y = __shfl_up(x, d, 64);
        if (lane >= d) x += y;
    }
    if (lane == 63) s_wave[wv] = x;
    __syncthreads();
    if (wv == 0 && lane < 4) {
        int y = s_wave[lane];
#pragma unroll
        for (int d = 1; d < 4; d <<= 1) {
            int z = __shfl_up(y, d, 64);
            if (lane >= d) y += z;
        }
        s_wave[lane] = y;
    }
    __syncthreads();
    int waveoff = (wv > 0) ? s_wave[wv - 1] : 0;
    if (i < n) {
        row_ptr[i + 1] = blk_base[blockIdx.x] + waveoff + x;
        inv[i] = 1.0f / (float)(v > 1 ? v : 1);
    }
    if (i == 0) row_ptr[0] = 0;
}

// Atomic-free placement: rec[row_ptr[dst]+rank[e]] = {src, ea}.
__global__ void place_kernel(const int* __restrict__ eidx, const float* __restrict__ ea,
                             const int* __restrict__ row_ptr, const int* __restrict__ rank,
                             fvec4* __restrict__ rec, int e_cnt) {
    int e = blockIdx.x * blockDim.x + threadIdx.x;
    if (e >= e_cnt) return;
    int src = eidx[e];
    int dst = eidx[e_cnt + e];
    int pos = row_ptr[dst] + rank[e];
    fvec4 r;
    r.x = __int_as_float(src);
    r.y = ea[3 * e];
    r.z = ea[3 * e + 1];
    r.w = ea[3 * e + 2];
    rec[pos] = r;
}

__global__ void h0_kernel(const float* __restrict__ x, const float* __restrict__ fc1_w,
                          const float* __restrict__ fc1_b, float* __restrict__ h, int n) {
    __shared__ float s_w[WN * 3];
    __shared__ float s_b[WN];
    int t = threadIdx.x;
    if (t < WN * 3) s_w[t] = fc1_w[t];
    if (t < WN) s_b[t] = fc1_b[t];
    __syncthreads();
    int i = blockIdx.x * blockDim.x + t;
    if (i >= n) return;
    float x0 = x[3 * i], x1 = x[3 * i + 1], x2 = x[3 * i + 2];
#pragma unroll
    for (int j = 0; j < WN; j++) {
        h[(size_t)i * WN + j] = s_b[j] + s_w[j * 3] * x0 + s_w[j * 3 + 1] * x1 + s_w[j * 3 + 2] * x2;
    }
}

// Cooperative gather (R6 structure) + batch-8 software-pipelined h-loads.
// 16 node-groups x 16 threads; thread owns channels (2tc, 2tc+1). Per
// 32-edge chunk: stage recs to LDS (hid recomputed in-register), then the
// inner loop issues 8 independent h-gathers before consuming them (8 loads
// in flight vs ~200-400cyc L2/L3 latency). s_root dropped: epilogue reads
// root (4KB) straight through L1 -> 21KB LDS -> 7 blocks/CU.
__global__ void gather2_kernel(const int* __restrict__ row_ptr, const fvec4* __restrict__ rec,
                               const float* __restrict__ h_in, float* __restrict__ h_out,
                               const float* __restrict__ inv,
                               const float* __restrict__ kw1, const float* __restrict__ kb1,
                               const float* __restrict__ kw2, const float* __restrict__ kb2,
                               const float* __restrict__ root, const float* __restrict__ cbias,
                               int n) {
    __shared__ float s_h[GPB * 34];          // group stride 34
    __shared__ int   s_src[GPB][33];         // group stride 33 -> distinct banks per group
    __shared__ fvec4 s_hid_u[GPB][33];       // 16B lane stride writes: conflict-free
    __shared__ fvec4 s_hid_v[GPB][33];
    __shared__ int   s_maxdeg;

    int t = threadIdx.x;
    if (t == 0) s_maxdeg = 0;

    int grp = t >> 4;          // 0..15
    int tc  = t & 15;          // 0..15, channels 2tc, 2tc+1
    int node = blockIdx.x * GPB + grp;
    bool valid = node < n;

    // per-thread weight columns for 2 output channels (16 floats, coalesced)
    const fvec4* kwp = (const fvec4*)(kw2 + tc * 16);
    fvec4 wa0 = kwp[0], wa1 = kwp[1];        // channel 2tc
    fvec4 wb0 = kwp[2], wb1 = kwp[3];        // channel 2tc+1
    float2 b2 = *(const float2*)(kb2 + 2 * tc);
    float2 cb = *(const float2*)(cbias + 2 * tc);

    int e0 = 0, e1 = 0;
    float2 hself = {0.0f, 0.0f};
    if (valid) {
        e0 = row_ptr[node];
        e1 = row_ptr[node + 1];
        hself = *(const float2*)(h_in + (size_t)node * WN + 2 * tc);
    }
    *(float2*)&s_h[grp * 34 + 2 * tc] = hself;
    int deg = e1 - e0;
    __syncthreads();                         // s_maxdeg init + s_h visible
    if (valid && tc == 0 && deg > 0) atomicMax(&s_maxdeg, deg);
    __syncthreads();
    int nchunk = (s_maxdeg + 31) >> 5;       // block-uniform

    float acc0 = 0.0f, acc1 = 0.0f;
    for (int cs = 0; cs < nchunk; cs++) {
        int ebase = e0 + (cs << 5);
        // stage 32 edges: 2 per thread, hid recomputed in-register
#pragma unroll
        for (int s = 0; s < 2; s++) {
            int li = tc + (s << 4);
            int e = ebase + li;
            if (e < e1) {
                fvec4 r = rec[e];
                s_src[grp][li] = __float_as_int(r.x);
                float hv[HID];
#pragma unroll
                for (int j = 0; j < HID; j++) {
                    float u = kb1[j] + kw1[3 * j] * r.y + kw1[3 * j + 1] * r.z + kw1[3 * j + 2] * r.w;
                    hv[j] = u > 0.0f ? u : 0.0f;
                }
                fvec4 lo, hi;
                lo.x = hv[0]; lo.y = hv[1]; lo.z = hv[2]; lo.w = hv[3];
                hi.x = hv[4]; hi.y = hv[5]; hi.z = hv[6]; hi.w = hv[7];
                s_hid_u[grp][li] = lo;
                s_hid_v[grp][li] = hi;
            }
        }
        __syncthreads();
        int rem = e1 - ebase;
        int cnt = rem < 32 ? rem : 32;       // <=0 for finished/invalid groups

        int i = 0;
        for (; i + 8 <= cnt; i += 8) {
            // batch: read 8 srcs (LDS broadcast), launch 8 independent h-loads
            int src[8];
#pragma unroll
            for (int k = 0; k < 8; k++) src[k] = s_src[grp][i + k];
            float2 hh[8];
#pragma unroll
            for (int k = 0; k < 8; k++)
                hh[k] = *(const float2*)(h_in + (size_t)src[k] * WN + 2 * tc);
            // consume: LDS hid reads + w arithmetic while loads complete
#pragma unroll
            for (int k = 0; k < 8; k++) {
                fvec4 u = s_hid_u[grp][i + k];
                fvec4 v = s_hid_v[grp][i + k];
                float w0 = b2.x + wa0.x * u.x + wa0.y * u.y + wa0.z * u.z + wa0.w * u.w
                                + wa1.x * v.x + wa1.y * v.y + wa1.z * v.z + wa1.w * v.w;
                float w1 = b2.y + wb0.x * u.x + wb0.y * u.y + wb0.z * u.z + wb0.w * u.w
                                + wb1.x * v.x + wb1.y * v.y + wb1.z * v.z + wb1.w * v.w;
                acc0 += hh[k].x * w0;
                acc1 += hh[k].y * w1;
            }
        }
        for (; i < cnt; i++) {
            int src = s_src[grp][i];
            fvec4 u = s_hid_u[grp][i];
            fvec4 v = s_hid_v[grp][i];
            float w0 = b2.x + wa0.x * u.x + wa0.y * u.y + wa0.z * u.z + wa0.w * u.w
                            + wa1.x * v.x + wa1.y * v.y + wa1.z * v.z + wa1.w * v.w;
            float w1 = b2.y + wb0.x * u.x + wb0.y * u.y + wb0.z * u.z + wb0.w * u.w
                            + wb1.x * v.x + wb1.y * v.y + wb1.z * v.z + wb1.w * v.w;
            float2 hh = *(const float2*)(h_in + (size_t)src * WN + 2 * tc);
            acc0 += hh.x * w0;
            acc1 += hh.y * w1;
        }
        __syncthreads();
    }
    if (!valid) return;

    float invn = inv[node];
    float r0 = acc0 * invn + cb.x;
    float r1 = acc1 * invn + cb.y;
#pragma unroll
    for (int k = 0; k < WN; k++) {
        float hk = s_h[grp * 34 + k];
        float2 rt = *(const float2*)(root + k * WN + 2 * tc);   // 4KB, L1-resident
        r0 += hk * rt.x;
        r1 += hk * rt.y;
    }
    float2 o;
    o.x = r0 > 0.0f ? r0 : 0.0f;
    o.y = r1 > 0.0f ? r1 : 0.0f;
    *(float2*)(h_out + (size_t)node * WN + 2 * tc) = o;
}

__global__ void out_kernel(const float* __restrict__ h, const float* __restrict__ fc2_w,
                           const float* __restrict__ fc2_b, float* __restrict__ out, int n) {
    __shared__ float s_w[WN];
    __shared__ float s_b;
    int t = threadIdx.x;
    if (t < WN) s_w[t] = fc2_w[t];
    if (t == 0) s_b = fc2_b[0];
    __syncthreads();
    int i = blockIdx.x * blockDim.x + t;
    if (i >= n) return;
    float acc = s_b;
#pragma unroll
    for (int k = 0; k < WN; k++) acc += h[(size_t)i * WN + k] * s_w[k];
    out[i] = acc;
}

extern "C" void kernel_launch(void* const* d_in, const int* in_sizes, int n_in,
                              void* d_out, int out_size, void* d_ws, size_t ws_size,
                              hipStream_t stream) {
    const float* x      = (const float*)d_in[0];
    const int*   eidx   = (const int*)d_in[1];
    const float* ea     = (const float*)d_in[2];
    const float* fc1_w  = (const float*)d_in[3];
    const float* fc1_b  = (const float*)d_in[4];
    const float* fc2_w  = (const float*)d_in[5];
    const float* fc2_b  = (const float*)d_in[6];
    const float* kw1    = (const float*)d_in[7];
    const float* kb1    = (const float*)d_in[8];
    const float* kw2    = (const float*)d_in[9];
    const float* kb2    = (const float*)d_in[10];
    const float* root   = (const float*)d_in[11];
    const float* cbias  = (const float*)d_in[12];
    float* out = (float*)d_out;

    const int n = in_sizes[0] / 3;       // 50000
    const int e_cnt = in_sizes[2] / 3;   // 1600000

    // workspace layout (floats, 16B-aligned sections)
    auto pad4 = [](size_t v) { return (v + 3) & ~(size_t)3; };
    float* ws = (float*)d_ws;
    size_t off = 0;
    float* hA       = ws + off; off += pad4((size_t)n * WN);
    float* hB       = ws + off; off += pad4((size_t)n * WN);
    float* inv      = ws + off; off += pad4(n);
    int*   cnt      = (int*)(ws + off); off += pad4(n);
    int*   row_ptr  = (int*)(ws + off); off += pad4(n + 1);
    int*   blk_sum  = (int*)(ws + off); off += pad4((n + 255) / 256);
    int*   blk_base = (int*)(ws + off); off += pad4((n + 255) / 256);
    int*   rank     = (int*)(ws + off); off += pad4(e_cnt);
    fvec4* rec      = (fvec4*)(ws + off); off += (size_t)4 * e_cnt;

    const int B = 256;
    int grid_n  = (n + B - 1) / B;
    int grid_e  = (e_cnt + B - 1) / B;
    int nblk    = (n + 255) / 256;
    int grid_g  = (n + GPB - 1) / GPB;

    zero_kernel<<<grid_n, B, 0, stream>>>(cnt, n);
    rank_kernel<<<grid_e, B, 0, stream>>>(eidx, cnt, rank, e_cnt);
    scan1_kernel<<<nblk, B, 0, stream>>>(cnt, blk_sum, n);
    scan2_kernel<<<1, B, 0, stream>>>(blk_sum, blk_base, nblk);
    scan3_kernel<<<nblk, B, 0, stream>>>(cnt, blk_base, row_ptr, inv, n);
    place_kernel<<<grid_e, B, 0, stream>>>(eidx, ea, row_ptr, rank, rec, e_cnt);
    h0_kernel<<<grid_n, B, 0, stream>>>(x, fc1_w, fc1_b, hA, n);

    float* hin = hA;
    float* hout = hB;
    for (int d = 0; d < DEPTH; d++) {
        for (int c = 0; c < 3; c++) {
            gather2_kernel<<<grid_g, B, 0, stream>>>(
                row_ptr, rec, hin, hout, inv,
                kw1 + (size_t)c * HID * 3, kb1 + (size_t)c * HID,
                kw2 + (size_t)c * WN * HID, kb2 + (size_t)c * WN,
                root + (size_t)c * WN * WN, cbias + (size_t)c * WN, n);
            float* tmp = hin; hin = hout; hout = tmp;
        }
    }
    // 12 swaps -> final h is in hin
    out_kernel<<<grid_n, B, 0, stream>>>(hin, fc2_w, fc2_b, out, n);
}

// Round 13
// 637.994 us; speedup vs baseline: 1.3197x; 1.3197x over previous
//
#include <hip/hip_runtime.h>

#define WN 32          // WIDTH
#define HID 8          // WIDTH/4
#define DEPTH 4
#define GPB 16         // node-groups per block (16 threads x 2 channels each) — R6-proven

typedef float fvec4 __attribute__((ext_vector_type(4)));

__global__ void zero_kernel(int* __restrict__ cnt, int n) {
    int i = blockIdx.x * blockDim.x + threadIdx.x;
    if (i < n) cnt[i] = 0;
}

// One atomic pass: per-node degree (cnt) AND each edge's within-segment rank.
__global__ void rank_kernel(const int* __restrict__ eidx, int* __restrict__ cnt,
                            int* __restrict__ rank, int e_cnt) {
    int e = blockIdx.x * blockDim.x + threadIdx.x;
    if (e >= e_cnt) return;
    rank[e] = atomicAdd(&cnt[eidx[e_cnt + e]], 1);
}

// --- 3-kernel parallel scan of cnt -> row_ptr (R8-proven) ---
__global__ void scan1_kernel(const int* __restrict__ cnt, int* __restrict__ blk_sum, int n) {
    __shared__ int s_wave[4];
    int t = threadIdx.x;
    int lane = t & 63, wv = t >> 6;
    int i = blockIdx.x * 256 + t;
    int v = (i < n) ? cnt[i] : 0;
#pragma unroll
    for (int d = 1; d < 64; d <<= 1) v += __shfl_xor(v, d, 64);
    if (lane == 0) s_wave[wv] = v;
    __syncthreads();
    if (t == 0) blk_sum[blockIdx.x] = s_wave[0] + s_wave[1] + s_wave[2] + s_wave[3];
}

__global__ void scan2_kernel(const int* __restrict__ blk_sum, int* __restrict__ blk_base, int nblk) {
    __shared__ int s_wave[4];
    int t = threadIdx.x;
    int lane = t & 63, wv = t >> 6;
    int offset = 0;
    for (int base = 0; base < nblk; base += 256) {
        int i = base + t;
        int v = (i < nblk) ? blk_sum[i] : 0;
        int x = v;
#pragma unroll
        for (int d = 1; d < 64; d <<= 1) {
            int y = __shfl_up(x, d, 64);
            if (lane >= d) x += y;
        }
        if (lane == 63) s_wave[wv] = x;
        __syncthreads();
        if (wv == 0 && lane < 4) {
            int y = s_wave[lane];
#pragma unroll
            for (int d = 1; d < 4; d <<= 1) {
                int z = __shfl_up(y, d, 64);
                if (lane >= d) y += z;
            }
            s_wave[lane] = y;
        }
        __syncthreads();
        int waveoff = (wv > 0) ? s_wave[wv - 1] : 0;
        int total = s_wave[3];
        if (i < nblk) blk_base[i] = x + waveoff + offset - v;   // exclusive
        offset += total;
        __syncthreads();
    }
}

__global__ void scan3_kernel(const int* __restrict__ cnt, const int* __restrict__ blk_base,
                             int* __restrict__ row_ptr, float* __restrict__ inv, int n) {
    __shared__ int s_wave[4];
    int t = threadIdx.x;
    int lane = t & 63, wv = t >> 6;
    int i = blockIdx.x * 256 + t;
    int v = (i < n) ? cnt[i] : 0;
    int x = v;
#pragma unroll
    for (int d = 1; d < 64; d <<= 1) {
        int y = __shfl_up(x, d, 64);
        if (lane >= d) x += y;
    }
    if (lane == 63) s_wave[wv] = x;
    __syncthreads();
    if (wv == 0 && lane < 4) {
        int y = s_wave[lane];
#pragma unroll
        for (int d = 1; d < 4; d <<= 1) {
            int z = __shfl_up(y, d, 64);
            if (lane >= d) y += z;
        }
        s_wave[lane] = y;
    }
    __syncthreads();
    int waveoff = (wv > 0) ? s_wave[wv - 1] : 0;
    if (i < n) {
        row_ptr[i + 1] = blk_base[blockIdx.x] + waveoff + x;
        inv[i] = 1.0f / (float)(v > 1 ? v : 1);
    }
    if (i == 0) row_ptr[0] = 0;
}

// Atomic-free placement: rec[row_ptr[dst]+rank[e]] = {src, ea}.
__global__ void place_kernel(const int* __restrict__ eidx, const float* __restrict__ ea,
                             const int* __restrict__ row_ptr, const int* __restrict__ rank,
                             fvec4* __restrict__ rec, int e_cnt) {
    int e = blockIdx.x * blockDim.x + threadIdx.x;
    if (e >= e_cnt) return;
    int src = eidx[e];
    int dst = eidx[e_cnt + e];
    int pos = row_ptr[dst] + rank[e];
    fvec4 r;
    r.x = __int_as_float(src);
    r.y = ea[3 * e];
    r.z = ea[3 * e + 1];
    r.w = ea[3 * e + 2];
    rec[pos] = r;
}

__global__ void h0_kernel(const float* __restrict__ x, const float* __restrict__ fc1_w,
                          const float* __restrict__ fc1_b, float* __restrict__ h, int n) {
    __shared__ float s_w[WN * 3];
    __shared__ float s_b[WN];
    int t = threadIdx.x;
    if (t < WN * 3) s_w[t] = fc1_w[t];
    if (t < WN) s_b[t] = fc1_b[t];
    __syncthreads();
    int i = blockIdx.x * blockDim.x + t;
    if (i >= n) return;
    float x0 = x[3 * i], x1 = x[3 * i + 1], x2 = x[3 * i + 2];
#pragma unroll
    for (int j = 0; j < WN; j++) {
        h[(size_t)i * WN + j] = s_b[j] + s_w[j * 3] * x0 + s_w[j * 3 + 1] * x1 + s_w[j * 3 + 2] * x2;
    }
}

// R10 cooperative gather with GROUP-INDEPENDENT chunking. 16 node-groups x
// 16 threads; thread owns channels (2tc, 2tc+1). Each quarter-wave group
// loops over ITS OWN degree (no block maxdeg, no per-chunk __syncthreads):
// LDS staging is produced & consumed by the same quarter-wave, so
// wave_barrier suffices (wave-synchronous LDS proven in R8). One prologue
// __syncthreads covers the block-shared s_root. Fused epilogue.
__global__ void gather2_kernel(const int* __restrict__ row_ptr, const fvec4* __restrict__ rec,
                               const float* __restrict__ h_in, float* __restrict__ h_out,
                               const float* __restrict__ inv,
                               const float* __restrict__ kw1, const float* __restrict__ kb1,
                               const float* __restrict__ kw2, const float* __restrict__ kb2,
                               const float* __restrict__ root, const float* __restrict__ cbias,
                               int n) {
    __shared__ float s_root[WN * 34];        // row stride 34: float2-aligned, conflict-free
    __shared__ float s_h[GPB * 34];          // group stride 34
    __shared__ int   s_src[GPB][33];         // group stride 33 -> distinct banks per group
    __shared__ fvec4 s_hid_u[GPB][33];       // 16B lane stride writes: conflict-free
    __shared__ fvec4 s_hid_v[GPB][33];

    int t = threadIdx.x;
    for (int i = t; i < WN * WN; i += 256) s_root[(i >> 5) * 34 + (i & 31)] = root[i];

    int grp = t >> 4;          // 0..15
    int tc  = t & 15;          // 0..15, channels 2tc, 2tc+1
    int node = blockIdx.x * GPB + grp;
    bool valid = node < n;

    // per-thread weight columns for 2 output channels (16 floats, coalesced)
    const fvec4* kwp = (const fvec4*)(kw2 + tc * 16);
    fvec4 wa0 = kwp[0], wa1 = kwp[1];        // channel 2tc
    fvec4 wb0 = kwp[2], wb1 = kwp[3];        // channel 2tc+1
    float2 b2 = *(const float2*)(kb2 + 2 * tc);
    float2 cb = *(const float2*)(cbias + 2 * tc);

    int e0 = 0, e1 = 0;
    float2 hself = {0.0f, 0.0f};
    if (valid) {
        e0 = row_ptr[node];
        e1 = row_ptr[node + 1];
        hself = *(const float2*)(h_in + (size_t)node * WN + 2 * tc);
    }
    *(float2*)&s_h[grp * 34 + 2 * tc] = hself;
    __syncthreads();                         // s_root visible to all waves (only block-wide sync)

    float acc0 = 0.0f, acc1 = 0.0f;
    for (int ebase = e0; ebase < e1; ebase += 32) {
        // stage up to 32 edges: 2 per thread, hid recomputed in-register
#pragma unroll
        for (int s = 0; s < 2; s++) {
            int li = tc + (s << 4);
            int e = ebase + li;
            if (e < e1) {
                fvec4 r = rec[e];
                s_src[grp][li] = __float_as_int(r.x);
                float hv[HID];
#pragma unroll
                for (int j = 0; j < HID; j++) {
                    float u = kb1[j] + kw1[3 * j] * r.y + kw1[3 * j + 1] * r.z + kw1[3 * j + 2] * r.w;
                    hv[j] = u > 0.0f ? u : 0.0f;
                }
                fvec4 lo, hi;
                lo.x = hv[0]; lo.y = hv[1]; lo.z = hv[2]; lo.w = hv[3];
                hi.x = hv[4]; hi.y = hv[5]; hi.z = hv[6]; hi.w = hv[7];
                s_hid_u[grp][li] = lo;
                s_hid_v[grp][li] = hi;
            }
        }
        __builtin_amdgcn_wave_barrier();     // producer==consumer quarter-wave: order pin only
        int rem = e1 - ebase;
        int cnt = rem < 32 ? rem : 32;
#pragma unroll 4
        for (int i = 0; i < cnt; i++) {
            int src = s_src[grp][i];
            fvec4 u = s_hid_u[grp][i];
            fvec4 v = s_hid_v[grp][i];
            float w0 = b2.x + wa0.x * u.x + wa0.y * u.y + wa0.z * u.z + wa0.w * u.w
                            + wa1.x * v.x + wa1.y * v.y + wa1.z * v.z + wa1.w * v.w;
            float w1 = b2.y + wb0.x * u.x + wb0.y * u.y + wb0.z * u.z + wb0.w * u.w
                            + wb1.x * v.x + wb1.y * v.y + wb1.z * v.z + wb1.w * v.w;
            float2 hh = *(const float2*)(h_in + (size_t)src * WN + 2 * tc);
            acc0 += hh.x * w0;
            acc1 += hh.y * w1;
        }
        __builtin_amdgcn_wave_barrier();     // reads done before next stage overwrites
    }
    if (!valid) return;

    float invn = inv[node];
    float r0 = acc0 * invn + cb.x;
    float r1 = acc1 * invn + cb.y;
#pragma unroll
    for (int k = 0; k < WN; k++) {
        float hk = s_h[grp * 34 + k];
        float2 rt = *(const float2*)&s_root[k * 34 + 2 * tc];
        r0 += hk * rt.x;
        r1 += hk * rt.y;
    }
    float2 o;
    o.x = r0 > 0.0f ? r0 : 0.0f;
    o.y = r1 > 0.0f ? r1 : 0.0f;
    *(float2*)(h_out + (size_t)node * WN + 2 * tc) = o;
}

__global__ void out_kernel(const float* __restrict__ h, const float* __restrict__ fc2_w,
                           const float* __restrict__ fc2_b, float* __restrict__ out, int n) {
    __shared__ float s_w[WN];
    __shared__ float s_b;
    int t = threadIdx.x;
    if (t < WN) s_w[t] = fc2_w[t];
    if (t == 0) s_b = fc2_b[0];
    __syncthreads();
    int i = blockIdx.x * blockDim.x + t;
    if (i >= n) return;
    float acc = s_b;
#pragma unroll
    for (int k = 0; k < WN; k++) acc += h[(size_t)i * WN + k] * s_w[k];
    out[i] = acc;
}

extern "C" void kernel_launch(void* const* d_in, const int* in_sizes, int n_in,
                              void* d_out, int out_size, void* d_ws, size_t ws_size,
                              hipStream_t stream) {
    const float* x      = (const float*)d_in[0];
    const int*   eidx   = (const int*)d_in[1];
    const float* ea     = (const float*)d_in[2];
    const float* fc1_w  = (const float*)d_in[3];
    const float* fc1_b  = (const float*)d_in[4];
    const float* fc2_w  = (const float*)d_in[5];
    const float* fc2_b  = (const float*)d_in[6];
    const float* kw1    = (const float*)d_in[7];
    const float* kb1    = (const float*)d_in[8];
    const float* kw2    = (const float*)d_in[9];
    const float* kb2    = (const float*)d_in[10];
    const float* root   = (const float*)d_in[11];
    const float* cbias  = (const float*)d_in[12];
    float* out = (float*)d_out;

    const int n = in_sizes[0] / 3;       // 50000
    const int e_cnt = in_sizes[2] / 3;   // 1600000

    // workspace layout (floats, 16B-aligned sections)
    auto pad4 = [](size_t v) { return (v + 3) & ~(size_t)3; };
    float* ws = (float*)d_ws;
    size_t off = 0;
    float* hA       = ws + off; off += pad4((size_t)n * WN);
    float* hB       = ws + off; off += pad4((size_t)n * WN);
    float* inv      = ws + off; off += pad4(n);
    int*   cnt      = (int*)(ws + off); off += pad4(n);
    int*   row_ptr  = (int*)(ws + off); off += pad4(n + 1);
    int*   blk_sum  = (int*)(ws + off); off += pad4((n + 255) / 256);
    int*   blk_base = (int*)(ws + off); off += pad4((n + 255) / 256);
    int*   rank     = (int*)(ws + off); off += pad4(e_cnt);
    fvec4* rec      = (fvec4*)(ws + off); off += (size_t)4 * e_cnt;

    const int B = 256;
    int grid_n  = (n + B - 1) / B;
    int grid_e  = (e_cnt + B - 1) / B;
    int nblk    = (n + 255) / 256;
    int grid_g  = (n + GPB - 1) / GPB;

    zero_kernel<<<grid_n, B, 0, stream>>>(cnt, n);
    rank_kernel<<<grid_e, B, 0, stream>>>(eidx, cnt, rank, e_cnt);
    scan1_kernel<<<nblk, B, 0, stream>>>(cnt, blk_sum, n);
    scan2_kernel<<<1, B, 0, stream>>>(blk_sum, blk_base, nblk);
    scan3_kernel<<<nblk, B, 0, stream>>>(cnt, blk_base, row_ptr, inv, n);
    place_kernel<<<grid_e, B, 0, stream>>>(eidx, ea, row_ptr, rank, rec, e_cnt);
    h0_kernel<<<grid_n, B, 0, stream>>>(x, fc1_w, fc1_b, hA, n);

    float* hin = hA;
    float* hout = hB;
    for (int d = 0; d < DEPTH; d++) {
        for (int c = 0; c < 3; c++) {
            gather2_kernel<<<grid_g, B, 0, stream>>>(
                row_ptr, rec, hin, hout, inv,
                kw1 + (size_t)c * HID * 3, kb1 + (size_t)c * HID,
                kw2 + (size_t)c * WN * HID, kb2 + (size_t)c * WN,
                root + (size_t)c * WN * WN, cbias + (size_t)c * WN, n);
            float* tmp = hin; hin = hout; hout = tmp;
        }
    }
    // 12 swaps -> final h is in hin
    out_kernel<<<grid_n, B, 0, stream>>>(hin, fc2_w, fc2_b, out, n);
}